// Round 14
// baseline (519.726 us; speedup 1.0000x reference)
//
#include <hip/hip_runtime.h>
#include <math.h>

#define N 256
#define BS 32
#define NB_ 8
#define EPS 1e-5f

// One block per batch, 1024 threads (16 waves/CU). Thread (ty,tx)=(tid>>5,tid&31)
// owns an 8x8 tile of M = L^T: rows [8ty,8ty+8), cols {4tx..+3} u {128+4tx..+3}.
// vs round 13 (passed, 459us): LOOKAHEAD — pivot block kb+1 is mini-updated
// from LDS panels (1 elem/thread) right after R' is formed, then wave 0
// inverts it CONCURRENTLY with the (d) trailing update of step kb. The ~10us
// serial fp64 inversion chain hides behind (d). R' ping-pongs RfA->RfB
// (removes the intra-(c) barrier). m parks into dead RfA during inversion.
__global__ __launch_bounds__(1024, 4) void mtt_fused(const float* __restrict__ x,
                                                     float* __restrict__ out) {
    constexpr int LDR = N + 8;
    __shared__ alignas(16) float  RfA[BS][LDR];    // Rold panel / x strip / park
    __shared__ alignas(16) float  RfB[BS][LDR];    // R' panel
    __shared__ alignas(16) float  CfT[BS][LDR];    // col panel, transposed
    __shared__ float  Pf[BS][BS + 1];              // inverted pivot fp32
    __shared__ float  Psn[BS][BS + 1];             // next pivot block (lookahead)
    __shared__ double dsum[4][N];                  // colsum partials
    __shared__ float  sdx[N];                      // exp(x[i][i])
    __shared__ float  sdiag_f[N];
    __shared__ float  sroot_f[N];
    __shared__ int    indx[BS];

    const int tid = threadIdx.x;
    const int ty = tid >> 5, tx = tid & 31;        // ty 0..31
    const int R0  = ty << 3;
    const int c0a = tx << 2;
    const int c0b = 128 + (tx << 2);
    const float* xb = x + (size_t)blockIdx.x * N * N;
    float* ob = out + (size_t)blockIdx.x * N * N;

    float m[8][8];

    // ===================== PHASE 1: build M = L^T =====================
    double csacc = 0.0;
    const int tq = tid >> 8, jc = tid & 255;
#pragma unroll 1
    for (int s = 0; s < 8; ++s) {
        {   // coalesced strip load: x rows [32s,32s+32) -> RfA
            const int rl = tid >> 5, cl = (tid & 31) << 3;
            const float* src = &xb[(size_t)(32 * s + rl) * N + cl];
            *(float4*)&RfA[rl][cl]     = *(const float4*)&src[0];
            *(float4*)&RfA[rl][cl + 4] = *(const float4*)&src[4];
        }
        __syncthreads();
#pragma unroll
        for (int r = 0; r < 8; ++r)
            csacc += (double)expf(RfA[(tq << 3) + r][jc]);
        if (tid < 32) sdx[32 * s + tid] = expf(RfA[tid][32 * s + tid]);
        if ((tx >> 3) == s) {               // first-half cols: strips 0-3
            const int jb = (tx & 7) << 2;
#pragma unroll
            for (int cc = 0; cc < 4; ++cc)
#pragma unroll
                for (int r = 0; r < 8; ++r)
                    m[r][cc] = -(expf(RfA[jb + cc][R0 + r]) + EPS);
        }
        if (s >= 4 && (tx >> 3) == s - 4) { // second-half cols: strips 4-7
            const int jb = (tx & 7) << 2;
#pragma unroll
            for (int cc = 0; cc < 4; ++cc)
#pragma unroll
                for (int r = 0; r < 8; ++r)
                    m[r][4 + cc] = -(expf(RfA[jb + cc][R0 + r]) + EPS);
        }
        __syncthreads();
    }
    dsum[tq][jc] = csacc;
    __syncthreads();
    if (tid < N)
        dsum[0][tid] = dsum[0][tid] + dsum[1][tid] + dsum[2][tid] + dsum[3][tid];
    __syncthreads();
    // diag override: M[i][i] = colsum_i (i>0)
    if (ty < 16) {
#pragma unroll
        for (int r = 0; r < 8; ++r) {
            const int i = R0 + r;
            if (tx == ((ty << 1) + (r >> 2)) && i != 0)
                m[r][r & 3] =
                    (float)(dsum[0][i] - (double)sdx[i] + 255.0 * (double)EPS);
        }
    } else {
#pragma unroll
        for (int r = 0; r < 8; ++r) {
            const int i = R0 + r;
            if (tx == (((ty - 16) << 1) + (r >> 2)))
                m[r][4 + (r & 3)] =
                    (float)(dsum[0][i] - (double)sdx[i] + 255.0 * (double)EPS);
        }
    }
    if (tx == 0) {   // col-0 override: M[i][0] = exp(x[i][i])
#pragma unroll
        for (int r = 0; r < 8; ++r) m[r][0] = sdx[R0 + r];
    }

    // ---- staging macros (panels for block kb; next-pivot tiles for kbn) ----
#define STAGE_PANELS(kb_)                                                      \
    do {                                                                       \
        const bool rO = (ty >> 2) == (kb_);                                    \
        const bool p0 = ((kb_) < 4) && ((tx >> 3) == (kb_));                   \
        const bool p1 = ((kb_) >= 4) && ((tx >> 3) == (kb_) - 4);              \
        const int lr_ = (ty & 3) << 3, lc_ = (tx & 7) << 2;                    \
        if (rO) {                                                              \
            for (int r = 0; r < 8; ++r) {                                      \
                *(float4*)&RfA[lr_ + r][c0a] =                                 \
                    make_float4(m[r][0], m[r][1], m[r][2], m[r][3]);           \
                *(float4*)&RfA[lr_ + r][c0b] =                                 \
                    make_float4(m[r][4], m[r][5], m[r][6], m[r][7]);           \
            }                                                                  \
        }                                                                      \
        if (p0) {                                                              \
            for (int cc = 0; cc < 4; ++cc) {                                   \
                *(float4*)&CfT[lc_ + cc][R0] =                                 \
                    make_float4(m[0][cc], m[1][cc], m[2][cc], m[3][cc]);       \
                *(float4*)&CfT[lc_ + cc][R0 + 4] =                             \
                    make_float4(m[4][cc], m[5][cc], m[6][cc], m[7][cc]);       \
            }                                                                  \
        }                                                                      \
        if (p1) {                                                              \
            for (int cc = 0; cc < 4; ++cc) {                                   \
                *(float4*)&CfT[lc_ + cc][R0] =                                 \
                    make_float4(m[0][4+cc], m[1][4+cc], m[2][4+cc], m[3][4+cc]); \
                *(float4*)&CfT[lc_ + cc][R0 + 4] =                             \
                    make_float4(m[4][4+cc], m[5][4+cc], m[6][4+cc], m[7][4+cc]); \
            }                                                                  \
        }                                                                      \
    } while (0)

#define STAGE_PSN(kbn_)                                                        \
    do {                                                                       \
        const bool rO = (ty >> 2) == (kbn_);                                   \
        const int lr_ = (ty & 3) << 3, lc_ = (tx & 7) << 2;                    \
        if (rO && (kbn_) < 4 && ((tx >> 3) == (kbn_))) {                       \
            for (int r = 0; r < 8; ++r)                                        \
                for (int cc = 0; cc < 4; ++cc)                                 \
                    Psn[lr_ + r][lc_ + cc] = m[r][cc];                         \
        }                                                                      \
        if (rO && (kbn_) >= 4 && ((tx >> 3) == (kbn_) - 4)) {                  \
            for (int r = 0; r < 8; ++r)                                        \
                for (int cc = 0; cc < 4; ++cc)                                 \
                    Psn[lr_ + r][lc_ + cc] = m[r][4 + cc];                     \
        }                                                                      \
    } while (0)

    // ---- wave-0 register-resident fp64 inversion of Psn -> Pf (+park) ----
#define INVERT_PSN(PARKBUF)                                                    \
    do {                                                                       \
        float* park = &PARKBUF[0][0];                                          \
        for (int r = 0; r < 8; ++r) {                                          \
            *(float4*)&park[tid * 66 + (r << 3)] =                             \
                make_float4(m[r][0], m[r][1], m[r][2], m[r][3]);               \
            *(float4*)&park[tid * 66 + (r << 3) + 4] =                         \
                make_float4(m[r][4], m[r][5], m[r][6], m[r][7]);               \
        }                                                                      \
        asm volatile("" ::: "memory");                                         \
        {                                                                      \
            const int l = tid;                                                 \
            const int row = l & 31;                                            \
            const int h = l >> 5, hb = h << 5;                                 \
            double p[16];                                                      \
            for (int j = 0; j < 16; ++j)                                       \
                p[j] = (double)Psn[row][(h << 4) + j];                         \
            for (int k2 = 0; k2 < BS; ++k2) {                                  \
                const int hk2 = k2 >> 4, jk2 = k2 & 15;                        \
                const double cand = p[jk2];                                    \
                double av = (h == hk2 && row >= k2) ? fabs(cand) : -1.0;       \
                double vv = cand;                                              \
                int idx = row;                                                 \
                for (int off = 1; off < 64; off <<= 1) {                       \
                    const double oav = __shfl_xor(av, off);                    \
                    const double ovv = __shfl_xor(vv, off);                    \
                    const int    oi  = __shfl_xor(idx, off);                   \
                    if (oav > av || (oav == av && oi < idx)) {                 \
                        av = oav; vv = ovv; idx = oi;                          \
                    }                                                          \
                }                                                              \
                const double pivinv = 1.0 / vv;                                \
                if (l == 0) indx[k2] = idx;                                    \
                const int prt = (row == k2) ? idx : ((row == idx) ? k2 : row); \
                const int sl2 = prt + hb;                                      \
                for (int j = 0; j < 16; ++j) p[j] = __shfl(p[j], sl2);         \
                const double scol = __shfl(p[jk2], row + (hk2 << 5));          \
                const int pl = k2 + hb;                                        \
                const bool isPivRow = (row == k2);                             \
                for (int j = 0; j < 16; ++j) {                                 \
                    const double prow = __shfl(p[j], pl);                      \
                    const bool isK2col = (h == hk2) && (j == jk2);             \
                    const double srw  = isK2col ? pivinv : prow * pivinv;      \
                    const double base = isK2col ? 0.0 : p[j];                  \
                    p[j] = isPivRow ? srw : fma(-scol, srw, base);             \
                }                                                              \
            }                                                                  \
            for (int j = 0; j < 16; ++j)                                       \
                Pf[row][(h << 4) + j] = (float)p[j];                           \
            if (l < 32) {                                                      \
                for (int k2 = BS - 1; k2 >= 0; --k2) {                         \
                    const int pp = indx[k2];                                   \
                    if (pp != k2) {                                            \
                        const float t = Pf[l][k2];                             \
                        Pf[l][k2] = Pf[l][pp];                                 \
                        Pf[l][pp] = t;                                         \
                    }                                                          \
                }                                                              \
            }                                                                  \
        }                                                                      \
        asm volatile("" ::: "memory");                                         \
        for (int r = 0; r < 8; ++r) {                                          \
            const float4 q0 = *(const float4*)&park[tid * 66 + (r << 3)];      \
            const float4 q1 = *(const float4*)&park[tid * 66 + (r << 3) + 4];  \
            m[r][0] = q0.x; m[r][1] = q0.y; m[r][2] = q0.z; m[r][3] = q0.w;    \
            m[r][4] = q1.x; m[r][5] = q1.y; m[r][6] = q1.z; m[r][7] = q1.w;    \
        }                                                                      \
    } while (0)

    // ===================== PROLOGUE: stage kb=0, invert P0 =================
    STAGE_PANELS(0);
    STAGE_PSN(0);
    __syncthreads();
    if (tid < 64) INVERT_PSN(RfB);     // RfB dead until first (c)
    __syncthreads();

    // ===================== PHASE 2: blocked GJ, lookahead ===================
#pragma unroll 1
    for (int kb = 0; kb < NB_; ++kb) {
        const bool rowOwner = (ty >> 2) == kb;
        const bool h0piv = (kb < 4) && ((tx >> 3) == kb);
        const bool h1piv = (kb >= 4) && ((tx >> 3) == kb - 4);
        const int lr = (ty & 3) << 3;
        const int lc = (tx & 7) << 2;
        const int kn0 = (kb + 1) << 5;          // next pivot block base col/row

        // ---- (a) stage panels (kb>0) + raw next-pivot tiles (kb<7) ----
        if (kb > 0) STAGE_PANELS(kb);
        if (kb < 7) STAGE_PSN(kb + 1);
        __syncthreads();   // bar1

        // ---- (c) R' = P * Rold : read RfA+Pf, write RfB ----
        {
            float a0[8];
#pragma unroll
            for (int c = 0; c < 8; ++c) a0[c] = 0.f;
#pragma unroll 2
            for (int mm = 0; mm < BS; ++mm) {
                const float p0 = Pf[ty][mm];
                const float4 r0 = *(const float4*)&RfA[mm][c0a];
                const float4 r1 = *(const float4*)&RfA[mm][c0b];
                a0[0] = fmaf(p0, r0.x, a0[0]);
                a0[1] = fmaf(p0, r0.y, a0[1]);
                a0[2] = fmaf(p0, r0.z, a0[2]);
                a0[3] = fmaf(p0, r0.w, a0[3]);
                a0[4] = fmaf(p0, r1.x, a0[4]);
                a0[5] = fmaf(p0, r1.y, a0[5]);
                a0[6] = fmaf(p0, r1.z, a0[6]);
                a0[7] = fmaf(p0, r1.w, a0[7]);
            }
            if (h0piv) {
#pragma unroll
                for (int cc = 0; cc < 4; ++cc) a0[cc] = Pf[ty][lc + cc];
            }
            if (h1piv) {
#pragma unroll
                for (int cc = 0; cc < 4; ++cc) a0[4 + cc] = Pf[ty][lc + cc];
            }
            *(float4*)&RfB[ty][c0a] = make_float4(a0[0], a0[1], a0[2], a0[3]);
            *(float4*)&RfB[ty][c0b] = make_float4(a0[4], a0[5], a0[6], a0[7]);
        }
        __syncthreads();   // bar3: R' ready in RfB

        // ---- lookahead mini-update: Psn -= C * R' (1 elem/thread) ----
        if (kb < 7) {
            const int i = ty, j = tx;
            float acc = Psn[i][j];
#pragma unroll 4
            for (int mm = 0; mm < BS; ++mm)
                acc = fmaf(-CfT[mm][kn0 + i], RfB[mm][kn0 + j], acc);
            Psn[i][j] = acc;
        }
        __syncthreads();   // bar4: Psn final

        // ---- (b-overlap) wave 0 inverts next pivot WHILE others run (d) ----
        if (kb < 7 && tid < 64) INVERT_PSN(RfA);   // RfA (Rold) dead after (c)

        // ---- (d) tile update ----
        if (rowOwner) {
#pragma unroll
            for (int r = 0; r < 8; ++r) {
                const float4 b0 = *(const float4*)&RfB[lr + r][c0a];
                const float4 b1 = *(const float4*)&RfB[lr + r][c0b];
                m[r][0] = b0.x; m[r][1] = b0.y; m[r][2] = b0.z; m[r][3] = b0.w;
                m[r][4] = b1.x; m[r][5] = b1.y; m[r][6] = b1.z; m[r][7] = b1.w;
            }
        } else {
            if (h0piv) {
#pragma unroll
                for (int r = 0; r < 8; ++r) {
                    m[r][0] = 0.f; m[r][1] = 0.f; m[r][2] = 0.f; m[r][3] = 0.f;
                }
            }
            if (h1piv) {
#pragma unroll
                for (int r = 0; r < 8; ++r) {
                    m[r][4] = 0.f; m[r][5] = 0.f; m[r][6] = 0.f; m[r][7] = 0.f;
                }
            }
#pragma unroll 2
            for (int mm = 0; mm < BS; ++mm) {
                const float4 rv0 = *(const float4*)&RfB[mm][c0a];
                const float4 rv1 = *(const float4*)&RfB[mm][c0b];
                const float4 cv0 = *(const float4*)&CfT[mm][R0];
                const float4 cv1 = *(const float4*)&CfT[mm][R0 + 4];
                const float cc8[8] = {cv0.x, cv0.y, cv0.z, cv0.w,
                                      cv1.x, cv1.y, cv1.z, cv1.w};
#pragma unroll
                for (int r = 0; r < 8; ++r) {
                    const float cr = -cc8[r];
                    m[r][0] = fmaf(cr, rv0.x, m[r][0]);
                    m[r][1] = fmaf(cr, rv0.y, m[r][1]);
                    m[r][2] = fmaf(cr, rv0.z, m[r][2]);
                    m[r][3] = fmaf(cr, rv0.w, m[r][3]);
                    m[r][4] = fmaf(cr, rv1.x, m[r][4]);
                    m[r][5] = fmaf(cr, rv1.y, m[r][5]);
                    m[r][6] = fmaf(cr, rv1.z, m[r][6]);
                    m[r][7] = fmaf(cr, rv1.w, m[r][7]);
                }
            }
        }
        __syncthreads();   // bar5: RfA/RfB/CfT/Psn free; Pf_next ready
    }

    // ===================== PHASE 3: epilogue =====================
    if (ty < 16) {
#pragma unroll
        for (int r = 0; r < 8; ++r) {
            const int i = R0 + r;
            if (tx == ((ty << 1) + (r >> 2))) sdiag_f[i] = m[r][r & 3];
        }
    } else {
#pragma unroll
        for (int r = 0; r < 8; ++r) {
            const int i = R0 + r;
            if (tx == (((ty - 16) << 1) + (r >> 2))) sdiag_f[i] = m[r][4 + (r & 3)];
        }
    }
    if (ty == 0) {
        *(float4*)&sroot_f[c0a] = make_float4(m[0][0], m[0][1], m[0][2], m[0][3]);
        *(float4*)&sroot_f[c0b] = make_float4(m[0][4], m[0][5], m[0][6], m[0][7]);
    }
    __syncthreads();

#pragma unroll
    for (int r = 0; r < 8; ++r) {
        const int a = R0 + r;
        const float rt = sroot_f[a];
        {
            const float4 x0 = *(const float4*)&xb[(size_t)a * N + c0a];
            float ov[4];
#pragma unroll
            for (int c = 0; c < 4; ++c) {
                const int b_ = c0a + c;
                const float e = expf((c == 0) ? x0.x : (c == 1) ? x0.y
                                    : (c == 2) ? x0.z : x0.w);
                float o = (b_ == 0) ? 0.0f : e * sdiag_f[b_];
                if (a != 0) o -= e * m[r][c];
                if (a == b_) o += e * rt;
                ov[c] = o;
            }
            *(float4*)&ob[(size_t)a * N + c0a] = make_float4(ov[0], ov[1], ov[2], ov[3]);
        }
        {
            const float4 x1 = *(const float4*)&xb[(size_t)a * N + c0b];
            float ov[4];
#pragma unroll
            for (int c = 0; c < 4; ++c) {
                const int b_ = c0b + c;
                const float e = expf((c == 0) ? x1.x : (c == 1) ? x1.y
                                    : (c == 2) ? x1.z : x1.w);
                float o = e * sdiag_f[b_];          // b_ >= 128, never col 0
                if (a != 0) o -= e * m[r][4 + c];
                if (a == b_) o += e * rt;
                ov[c] = o;
            }
            *(float4*)&ob[(size_t)a * N + c0b] = make_float4(ov[0], ov[1], ov[2], ov[3]);
        }
    }
}

extern "C" void kernel_launch(void* const* d_in, const int* in_sizes, int n_in,
                              void* d_out, int out_size, void* d_ws, size_t ws_size,
                              hipStream_t stream) {
    const float* x = (const float*)d_in[0];
    float* out = (float*)d_out;
    mtt_fused<<<256, 1024, 0, stream>>>(x, out);
}